// Round 1
// baseline (1433.264 us; speedup 1.0000x reference)
//
#include <hip/hip_runtime.h>
#include <hip/hip_bf16.h>

#define CCH 384
#define HH 192
#define WW 192
#define NIMG 2
#define HWP (HH * WW)        // 36864 pixels per image
#define HEADS 12
#define HD 32
#define NWIN 24              // windows per axis (192/8)

// ---------------------------------------------------------------------------
// Kernel 1: depthwise 3x3 (zero-pad 1) + bias for q,k,v in one pass over x.
// One block per (n, c, h) row, 192 threads = one per w.
// ---------------------------------------------------------------------------
__global__ __launch_bounds__(192) void dwconv3_kernel(
    const float* __restrict__ x,
    const float* __restrict__ qw, const float* __restrict__ qb,
    const float* __restrict__ kw, const float* __restrict__ kb,
    const float* __restrict__ vw, const float* __restrict__ vb,
    float* __restrict__ yq, float* __restrict__ yk, float* __restrict__ yv)
{
    int bid = blockIdx.x;            // n*C*H + c*H + h
    int h  = bid % HH;
    int nc = bid / HH;
    int c  = nc % CCH;
    int w  = threadIdx.x;
    const float* xp = x + (size_t)nc * HWP;

    float sq = 0.f, sk = 0.f, sv = 0.f;
#pragma unroll
    for (int dy = -1; dy <= 1; ++dy) {
        int hh = h + dy;
        bool okh = (hh >= 0) && (hh < HH);
#pragma unroll
        for (int dx = -1; dx <= 1; ++dx) {
            int w2 = w + dx;
            bool ok = okh && (w2 >= 0) && (w2 < WW);
            float val = ok ? xp[hh * WW + w2] : 0.f;
            int wi = c * 9 + (dy + 1) * 3 + (dx + 1);
            sq = fmaf(val, qw[wi], sq);
            sk = fmaf(val, kw[wi], sk);
            sv = fmaf(val, vw[wi], sv);
        }
    }
    size_t o = (size_t)nc * HWP + (size_t)h * WW + w;
    yq[o] = sq + qb[c];
    yk[o] = sk + kb[c];
    yv[o] = sv + vb[c];
}

// ---------------------------------------------------------------------------
// Kernel 2: pointwise conv as SGEMM.  Out[n][m][p] = (sum_k W[m][k]*Y[n][k][p]
//           + bias[m]) * scale.   M=K=384, P=36864, grid.z = image.
// 128x128 tile, BK=16, 256 threads, 8x8 microtile (split 4+4 rows/cols).
// ---------------------------------------------------------------------------
#define BM 128
#define BP 128
#define BK 16

__global__ __launch_bounds__(256) void pw_gemm_kernel(
    const float* __restrict__ Y,    // [NIMG][384][P]
    const float* __restrict__ Wm,   // [384][384] row-major (out_c, in_c)
    const float* __restrict__ bias, // [384]
    float scale,
    float* __restrict__ Out)        // [NIMG][384][P]
{
    __shared__ float Ws[BK][BM + 4];   // stride 132 (16B-aligned rows)
    __shared__ float Ys[BK][BP + 4];

    const int P = HWP;
    int tid = threadIdx.x;
    int pp  = blockIdx.x * BP;
    int pm  = blockIdx.y * BM;
    size_t ioff = (size_t)blockIdx.z * CCH * P;
    Y   += ioff;
    Out += ioff;

    int tr = (tid >> 4) << 2;    // 0..60 step 4
    int tc = (tid & 15) << 2;    // 0..60 step 4

    float acc[8][8];
#pragma unroll
    for (int i = 0; i < 8; ++i)
#pragma unroll
        for (int j = 0; j < 8; ++j) acc[i][j] = 0.f;

    int wm = tid >> 1;           // 0..127
    int wk = (tid & 1) << 3;     // 0 or 8
    int yk = tid >> 5;           // 0..7
    int yp = (tid & 31) << 2;    // 0..124

    for (int k0 = 0; k0 < CCH; k0 += BK) {
        // stage W tile (transposed into LDS)
        const float* wsrc = Wm + (size_t)(pm + wm) * CCH + k0 + wk;
        float4 w0 = *(const float4*)wsrc;
        float4 w1 = *(const float4*)(wsrc + 4);
        Ws[wk + 0][wm] = w0.x; Ws[wk + 1][wm] = w0.y;
        Ws[wk + 2][wm] = w0.z; Ws[wk + 3][wm] = w0.w;
        Ws[wk + 4][wm] = w1.x; Ws[wk + 5][wm] = w1.y;
        Ws[wk + 6][wm] = w1.z; Ws[wk + 7][wm] = w1.w;
        // stage Y tile
        const float* ysrc = Y + (size_t)(k0 + yk) * P + pp + yp;
        *(float4*)&Ys[yk][yp]     = *(const float4*)ysrc;
        *(float4*)&Ys[yk + 8][yp] = *(const float4*)(ysrc + (size_t)8 * P);
        __syncthreads();

#pragma unroll
        for (int kk = 0; kk < BK; ++kk) {
            float a[8], b[8];
            *(float4*)(a)     = *(const float4*)&Ws[kk][tr];
            *(float4*)(a + 4) = *(const float4*)&Ws[kk][tr + 64];
            *(float4*)(b)     = *(const float4*)&Ys[kk][tc];
            *(float4*)(b + 4) = *(const float4*)&Ys[kk][tc + 64];
#pragma unroll
            for (int i = 0; i < 8; ++i)
#pragma unroll
                for (int j = 0; j < 8; ++j)
                    acc[i][j] = fmaf(a[i], b[j], acc[i][j]);
        }
        __syncthreads();
    }

#pragma unroll
    for (int ih = 0; ih < 2; ++ih) {
#pragma unroll
        for (int i2 = 0; i2 < 4; ++i2) {
            int i = ih * 4 + i2;
            int m = pm + tr + ih * 64 + i2;
            float bv = bias[m];
            float4 o0, o1;
            o0.x = (acc[i][0] + bv) * scale;
            o0.y = (acc[i][1] + bv) * scale;
            o0.z = (acc[i][2] + bv) * scale;
            o0.w = (acc[i][3] + bv) * scale;
            o1.x = (acc[i][4] + bv) * scale;
            o1.y = (acc[i][5] + bv) * scale;
            o1.z = (acc[i][6] + bv) * scale;
            o1.w = (acc[i][7] + bv) * scale;
            float* op = Out + (size_t)m * P + pp;
            *(float4*)(op + tc)      = o0;
            *(float4*)(op + tc + 64) = o1;
        }
    }
}

// ---------------------------------------------------------------------------
// Kernel 3: 8x8 window attention, one block per (window, head).
// S = q k^T + relpos bias; softmax rows; O = S v.  All fp32 in LDS.
// ---------------------------------------------------------------------------
__global__ __launch_bounds__(256) void attn_kernel(
    const float* __restrict__ q, const float* __restrict__ k,
    const float* __restrict__ v, const float* __restrict__ rpb,
    float* __restrict__ o)
{
    __shared__ float qs[64][36];
    __shared__ float ks[64][36];
    __shared__ float vs[64][36];
    __shared__ float S[64][68];

    int tid  = threadIdx.x;
    int head = blockIdx.y;
    int widx = blockIdx.x;
    int n    = widx / (NWIN * NWIN);
    int wrem = widx - n * (NWIN * NWIN);
    int wy   = wrem / NWIN;
    int wx   = wrem - wy * NWIN;

    size_t ioff = (size_t)n * CCH * HWP;
    int h0 = wy * 8, w0 = wx * 8;
    int d  = tid >> 3;       // 0..31
    int xi = tid & 7;        // 0..7
    size_t base = ioff + (size_t)(head * HD + d) * HWP + (size_t)h0 * WW + w0 + xi;

#pragma unroll
    for (int yi = 0; yi < 8; ++yi) {
        size_t g = base + (size_t)yi * WW;
        int t = yi * 8 + xi;
        qs[t][d] = q[g];
        ks[t][d] = k[g];
        vs[t][d] = v[g];
    }
    __syncthreads();

    // ---- scores + bias ----
    int i  = tid & 63;
    int jq = tid >> 6;
    float qr[32];
#pragma unroll
    for (int dq = 0; dq < 8; ++dq)
        *(float4*)&qr[dq * 4] = *(const float4*)&qs[i][dq * 4];
    int iy = i >> 3, ix = i & 7;
#pragma unroll
    for (int jj = 0; jj < 16; ++jj) {
        int j = jq * 16 + jj;
        float s = 0.f;
#pragma unroll
        for (int dq = 0; dq < 8; ++dq) {
            float4 kv = *(const float4*)&ks[j][dq * 4];
            s = fmaf(qr[dq * 4 + 0], kv.x, s);
            s = fmaf(qr[dq * 4 + 1], kv.y, s);
            s = fmaf(qr[dq * 4 + 2], kv.z, s);
            s = fmaf(qr[dq * 4 + 3], kv.w, s);
        }
        int dy = iy - (j >> 3) + 7;
        int dx = ix - (j & 7) + 7;
        s += rpb[(dy * 15 + dx) * HEADS + head];
        S[i][j] = s;
    }
    __syncthreads();

    // ---- softmax rows (4 lanes per row) ----
    {
        int row = jq * 16 + ((tid & 63) >> 2);
        int jc  = tid & 3;
        float m = -1e30f;
#pragma unroll
        for (int jj = 0; jj < 16; ++jj) m = fmaxf(m, S[row][jc + 4 * jj]);
        m = fmaxf(m, __shfl_xor(m, 1));
        m = fmaxf(m, __shfl_xor(m, 2));
        float sum = 0.f;
#pragma unroll
        for (int jj = 0; jj < 16; ++jj) {
            float e = __expf(S[row][jc + 4 * jj] - m);
            S[row][jc + 4 * jj] = e;
            sum += e;
        }
        sum += __shfl_xor(sum, 1);
        sum += __shfl_xor(sum, 2);
        float inv = 1.f / sum;
#pragma unroll
        for (int jj = 0; jj < 16; ++jj) S[row][jc + 4 * jj] *= inv;
    }
    __syncthreads();

    // ---- O = S * V ----
    float acc[8];
#pragma unroll
    for (int yi = 0; yi < 8; ++yi) acc[yi] = 0.f;
#pragma unroll
    for (int jb = 0; jb < 16; ++jb) {
        float v0 = vs[jb * 4 + 0][d];
        float v1 = vs[jb * 4 + 1][d];
        float v2 = vs[jb * 4 + 2][d];
        float v3 = vs[jb * 4 + 3][d];
#pragma unroll
        for (int yi = 0; yi < 8; ++yi) {
            float4 sv = *(const float4*)&S[yi * 8 + xi][jb * 4];
            acc[yi] = fmaf(sv.x, v0, acc[yi]);
            acc[yi] = fmaf(sv.y, v1, acc[yi]);
            acc[yi] = fmaf(sv.z, v2, acc[yi]);
            acc[yi] = fmaf(sv.w, v3, acc[yi]);
        }
    }
#pragma unroll
    for (int yi = 0; yi < 8; ++yi)
        o[base + (size_t)yi * WW] = acc[yi];
}

// ---------------------------------------------------------------------------
extern "C" void kernel_launch(void* const* d_in, const int* in_sizes, int n_in,
                              void* d_out, int out_size, void* d_ws, size_t ws_size,
                              hipStream_t stream) {
    const float* vid  = (const float*)d_in[0];
    const float* qd_w = (const float*)d_in[1];
    const float* qd_b = (const float*)d_in[2];
    const float* qp_w = (const float*)d_in[3];
    const float* qp_b = (const float*)d_in[4];
    const float* kd_w = (const float*)d_in[5];
    const float* kd_b = (const float*)d_in[6];
    const float* kp_w = (const float*)d_in[7];
    const float* kp_b = (const float*)d_in[8];
    const float* vd_w = (const float*)d_in[9];
    const float* vd_b = (const float*)d_in[10];
    const float* vp_w = (const float*)d_in[11];
    const float* vp_b = (const float*)d_in[12];
    const float* rpb  = (const float*)d_in[13];
    const float* pj_w = (const float*)d_in[14];
    const float* pj_b = (const float*)d_in[15];
    float* out = (float*)d_out;

    const size_t S1 = (size_t)NIMG * CCH * HWP;   // elems per staging buffer
    float* bufA = (float*)d_ws;                   // yq -> k
    float* bufB = bufA + S1;                      // yk -> v
    float* bufC = bufB + S1;                      // yv -> attn out
    float* bufD = bufC + S1;                      // q

    // 1) depthwise convs (all three at once)
    dwconv3_kernel<<<dim3(NIMG * CCH * HH), 192, 0, stream>>>(
        vid, qd_w, qd_b, kd_w, kd_b, vd_w, vd_b, bufA, bufB, bufC);

    // 2) pointwise GEMMs
    dim3 gg(HWP / BP, CCH / BM, NIMG);
    const float scale = 0.17677669529663687f;     // 32^-0.5 folded into q
    pw_gemm_kernel<<<gg, 256, 0, stream>>>(bufA, qp_w, qp_b, scale, bufD);
    pw_gemm_kernel<<<gg, 256, 0, stream>>>(bufB, kp_w, kp_b, 1.0f, bufA);
    pw_gemm_kernel<<<gg, 256, 0, stream>>>(bufC, vp_w, vp_b, 1.0f, bufB);

    // 3) window attention
    attn_kernel<<<dim3(NIMG * NWIN * NWIN, HEADS), 256, 0, stream>>>(
        bufD, bufA, bufB, rpb, bufC);

    // 4) output projection
    pw_gemm_kernel<<<gg, 256, 0, stream>>>(bufC, pj_w, pj_b, 1.0f, out);
}

// Round 2
// 482.011 us; speedup vs baseline: 2.9735x; 2.9735x over previous
//
#include <hip/hip_runtime.h>

#define CCH 384
#define HH 192
#define WWD 192
#define NIMG 2
#define HWP (HH * WWD)        // 36864 pixels per image
#define PTOT (NIMG * HWP)     // 73728
#define HEADS 12
#define HD 32
#define NWIN 24
#define WINS 576              // windows per image
#define EELEM ((size_t)NIMG * CCH * HWP)   // elems per tensor (28,311,552)
#define WMAT 147456           // 384*384

typedef __attribute__((ext_vector_type(8))) short bh8;            // 8 bf16 (MFMA frag)
typedef __attribute__((ext_vector_type(8))) unsigned short us8;
typedef __attribute__((ext_vector_type(4))) unsigned short us4;
typedef __attribute__((ext_vector_type(4))) float fx4;

__device__ __forceinline__ unsigned short f2bf(float f) {
    unsigned u = __float_as_uint(f);
    u += 0x7fffu + ((u >> 16) & 1u);      // round-to-nearest-even
    return (unsigned short)(u >> 16);
}

// ---------------------------------------------------------------------------
// weights fp32 -> bf16 (qp_w, kp_w, vp_w, proj_w concatenated)
// ---------------------------------------------------------------------------
__global__ __launch_bounds__(256) void wcvt(
    const float* __restrict__ a, const float* __restrict__ b,
    const float* __restrict__ c, const float* __restrict__ d,
    unsigned short* __restrict__ o)
{
    int idx8 = (blockIdx.x * 256 + threadIdx.x) * 8;   // 288 blocks * 256 * 8 = 589824 exact
    int which = idx8 / WMAT;
    int loc = idx8 - which * WMAT;
    const float* s = (which == 0) ? a : (which == 1) ? b : (which == 2) ? c : d;
    float4 v0 = *(const float4*)(s + loc);
    float4 v1 = *(const float4*)(s + loc + 4);
    us8 ov;
    ov[0] = f2bf(v0.x); ov[1] = f2bf(v0.y); ov[2] = f2bf(v0.z); ov[3] = f2bf(v0.w);
    ov[4] = f2bf(v1.x); ov[5] = f2bf(v1.y); ov[6] = f2bf(v1.z); ov[7] = f2bf(v1.w);
    *(us8*)(o + idx8) = ov;
}

// ---------------------------------------------------------------------------
// depthwise 3x3 + bias for q,k,v; input fp32 [n][c][h][w], output bf16 [n*c][p_std]
// one block per (n,c,h), 192 threads (one per w)
// ---------------------------------------------------------------------------
__global__ __launch_bounds__(192) void dwconv3(
    const float* __restrict__ x,
    const float* __restrict__ qw, const float* __restrict__ qb,
    const float* __restrict__ kw, const float* __restrict__ kb,
    const float* __restrict__ vw, const float* __restrict__ vb,
    unsigned short* __restrict__ oq, unsigned short* __restrict__ ok,
    unsigned short* __restrict__ ov)
{
    int bid = blockIdx.x;            // n*C*H + c*H + h
    int h  = bid % HH;
    int nc = bid / HH;
    int c  = nc % CCH;
    int w  = threadIdx.x;
    const float* xp = x + (size_t)nc * HWP;

    float sq = 0.f, sk = 0.f, sv = 0.f;
#pragma unroll
    for (int dy = -1; dy <= 1; ++dy) {
        int hh = h + dy;
        bool okh = (hh >= 0) && (hh < HH);
#pragma unroll
        for (int dx = -1; dx <= 1; ++dx) {
            int w2 = w + dx;
            bool okk = okh && (w2 >= 0) && (w2 < WWD);
            float val = okk ? xp[hh * WWD + w2] : 0.f;
            int wi = c * 9 + (dy + 1) * 3 + (dx + 1);
            sq = fmaf(val, qw[wi], sq);
            sk = fmaf(val, kw[wi], sk);
            sv = fmaf(val, vw[wi], sv);
        }
    }
    size_t o = (size_t)nc * HWP + (size_t)h * WWD + w;
    oq[o] = f2bf(sq + qb[c]);
    ok[o] = f2bf(sk + kb[c]);
    ov[o] = f2bf(sv + vb[c]);
}

// ---------------------------------------------------------------------------
// layout change: bf16 [n*c][p_std] -> bf16 [p_windowgathered][384] for q,k,v.
// block = (n*192 + h, cb of 64 channels); LDS 64x193 u16.
// ---------------------------------------------------------------------------
__global__ __launch_bounds__(256) void trsp(
    const unsigned short* __restrict__ s0, const unsigned short* __restrict__ s1,
    const unsigned short* __restrict__ s2,
    unsigned short* __restrict__ d0, unsigned short* __restrict__ d1,
    unsigned short* __restrict__ d2)
{
    __shared__ unsigned short T[64][193];
    int bx = blockIdx.x;
    int n = bx / HH, h = bx % HH;
    int cb = blockIdx.y;
    int tid = threadIdx.x;

    for (int ten = 0; ten < 3; ++ten) {
        const unsigned short* src = (ten == 0) ? s0 : (ten == 1) ? s1 : s2;
        unsigned short* dst = (ten == 0) ? d0 : (ten == 1) ? d1 : d2;
#pragma unroll
        for (int it = 0; it < 6; ++it) {
            int idx = it * 256 + tid;          // 1536 chunks of 8
            int cl = idx / 24, w8 = idx % 24;
            us8 v = *(const us8*)(src + (size_t)(n * CCH + cb * 64 + cl) * HWP
                                      + h * WWD + w8 * 8);
#pragma unroll
            for (int i = 0; i < 8; ++i) T[cl][w8 * 8 + i] = v[i];
        }
        __syncthreads();
#pragma unroll
        for (int it = 0; it < 3; ++it) {
            int job = it * 256 + tid;          // 768 jobs: (w, 16c-chunk)
            int w = job >> 2, ch = job & 3;
            int pwg = n * HWP + ((h >> 3) * NWIN + (w >> 3)) * 64 + (h & 7) * 8 + (w & 7);
            us8 lo, hi;
#pragma unroll
            for (int i = 0; i < 8; ++i) lo[i] = T[ch * 16 + i][w];
#pragma unroll
            for (int i = 0; i < 8; ++i) hi[i] = T[ch * 16 + 8 + i][w];
            unsigned short* dp = dst + (size_t)pwg * CCH + cb * 64 + ch * 16;
            *(us8*)dp = lo;
            *(us8*)(dp + 8) = hi;
        }
        __syncthreads();
    }
}

// ---------------------------------------------------------------------------
// bf16 MFMA GEMM over channels. Y: bf16 [p_wg][384] (k contiguous).
// W: bf16 [c_out][384]. 128x128 tile, BK=32, 4 waves, 4x4 16x16 frags/wave.
// ORIENT 1: D[c][p] -> out bf16 [p][c], (acc+bias)*scale      (q, k)
// ORIENT 2: D[p][c] -> out bf16 [n][c][p_local], acc+bias     (v, transposed for attn)
// ORIENT 3: D[p][c] -> out fp32 standard [n][c][h][w], un-gather windows (proj)
// ---------------------------------------------------------------------------
template<int ORIENT>
__global__ __launch_bounds__(256) void pw_gemm(
    const unsigned short* __restrict__ Y, const unsigned short* __restrict__ Wb,
    const float* __restrict__ bias, float scale,
    unsigned short* __restrict__ outb, float* __restrict__ outf)
{
    __shared__ unsigned short Wt[128][40];   // [c_out rows][k], padded
    __shared__ unsigned short Yt[128][40];   // [p rows][k], padded

    int tid = threadIdx.x;
    int pp0 = blockIdx.x * 128;
    int cm0 = blockIdx.y * 128;
    int lid = tid & 63, wid = tid >> 6;
    int wr = wid >> 1, wc = wid & 1;
    int li = lid & 15, g = lid >> 4;
    int srow = tid >> 2;                 // 0..63
    int skoff = (tid & 3) * 8;           // 0,8,16,24

    fx4 acc[4][4];
#pragma unroll
    for (int i = 0; i < 4; ++i)
#pragma unroll
        for (int j = 0; j < 4; ++j) acc[i][j] = (fx4){0.f, 0.f, 0.f, 0.f};

    const unsigned short* WpG = Wb + (size_t)(cm0 + srow) * CCH + skoff;
    const unsigned short* YpG = Y  + (size_t)(pp0 + srow) * CCH + skoff;
    bh8 w0 = *(const bh8*)(WpG);
    bh8 w1 = *(const bh8*)(WpG + (size_t)64 * CCH);
    bh8 y0 = *(const bh8*)(YpG);
    bh8 y1 = *(const bh8*)(YpG + (size_t)64 * CCH);

    typedef unsigned short (*tile_t)[40];
    tile_t Asrc = (ORIENT == 1) ? Wt : Yt;
    tile_t Bsrc = (ORIENT == 1) ? Yt : Wt;

    for (int kt = 0; kt < 12; ++kt) {
        __syncthreads();
        *(bh8*)&Wt[srow][skoff]      = w0;
        *(bh8*)&Wt[64 + srow][skoff] = w1;
        *(bh8*)&Yt[srow][skoff]      = y0;
        *(bh8*)&Yt[64 + srow][skoff] = y1;
        __syncthreads();
        if (kt < 11) {
            int ko = (kt + 1) * 32;
            w0 = *(const bh8*)(WpG + ko);
            w1 = *(const bh8*)(WpG + ko + (size_t)64 * CCH);
            y0 = *(const bh8*)(YpG + ko);
            y1 = *(const bh8*)(YpG + ko + (size_t)64 * CCH);
        }
        bh8 a[4], b[4];
#pragma unroll
        for (int mf = 0; mf < 4; ++mf)
            a[mf] = *(const bh8*)&Asrc[wr * 64 + mf * 16 + li][g * 8];
#pragma unroll
        for (int nf = 0; nf < 4; ++nf)
            b[nf] = *(const bh8*)&Bsrc[wc * 64 + nf * 16 + li][g * 8];
#pragma unroll
        for (int mf = 0; mf < 4; ++mf)
#pragma unroll
            for (int nf = 0; nf < 4; ++nf)
                acc[mf][nf] = __builtin_amdgcn_mfma_f32_16x16x32_bf16(
                    a[mf], b[nf], acc[mf][nf], 0, 0, 0);
    }

    if (ORIENT == 1) {
#pragma unroll
        for (int mf = 0; mf < 4; ++mf) {
            int c = cm0 + wr * 64 + mf * 16 + g * 4;
            float4 bv = *(const float4*)&bias[c];
#pragma unroll
            for (int nf = 0; nf < 4; ++nf) {
                int p = pp0 + wc * 64 + nf * 16 + li;
                us4 o;
                o[0] = f2bf((acc[mf][nf][0] + bv.x) * scale);
                o[1] = f2bf((acc[mf][nf][1] + bv.y) * scale);
                o[2] = f2bf((acc[mf][nf][2] + bv.z) * scale);
                o[3] = f2bf((acc[mf][nf][3] + bv.w) * scale);
                *(us4*)(outb + (size_t)p * CCH + c) = o;
            }
        }
    } else if (ORIENT == 2) {
#pragma unroll
        for (int nf = 0; nf < 4; ++nf) {
            int c = cm0 + wc * 64 + nf * 16 + li;
            float bv = bias[c];
#pragma unroll
            for (int mf = 0; mf < 4; ++mf) {
                int p = pp0 + wr * 64 + mf * 16 + g * 4;
                int n = p / HWP;
                int pl = p - n * HWP;
                us4 o;
                o[0] = f2bf(acc[mf][nf][0] + bv);
                o[1] = f2bf(acc[mf][nf][1] + bv);
                o[2] = f2bf(acc[mf][nf][2] + bv);
                o[3] = f2bf(acc[mf][nf][3] + bv);
                *(us4*)(outb + (size_t)(n * CCH + c) * HWP + pl) = o;
            }
        }
    } else {   // ORIENT 3: fp32 std layout, inverse window gather
#pragma unroll
        for (int nf = 0; nf < 4; ++nf) {
            int c = cm0 + wc * 64 + nf * 16 + li;
            float bv = bias[c];
#pragma unroll
            for (int mf = 0; mf < 4; ++mf) {
                int p = pp0 + wr * 64 + mf * 16 + g * 4;
                int n = p / HWP;
                int rem = p - n * HWP;
                int win = rem >> 6, t = rem & 63;
                int h = (win / NWIN) * 8 + (t >> 3);
                int w = (win % NWIN) * 8 + (t & 7);
                float4 o;
                o.x = acc[mf][nf][0] + bv;
                o.y = acc[mf][nf][1] + bv;
                o.z = acc[mf][nf][2] + bv;
                o.w = acc[mf][nf][3] + bv;
                *(float4*)(outf + (size_t)(n * CCH + c) * HWP + h * WWD + w) = o;
            }
        }
    }
}

// ---------------------------------------------------------------------------
// MFMA window attention. block = one window (64 tokens); 4 waves x 3 heads.
// q,k: bf16 [p_wg][384]; v: bf16 [n][c][p_local] (= V^T); out: bf16 [p_wg][384].
// ---------------------------------------------------------------------------
__global__ __launch_bounds__(256) void attn(
    const unsigned short* __restrict__ q, const unsigned short* __restrict__ k,
    const unsigned short* __restrict__ v, const float* __restrict__ rpb,
    unsigned short* __restrict__ o)
{
    __shared__ float rpbs[225 * HEADS];
    __shared__ unsigned short Pl[4][64][72];

    int tid = threadIdx.x, lid = tid & 63, wid = tid >> 6;
    int wl = blockIdx.x;
    int n = wl / WINS, winl = wl - n * WINS;
    int li = lid & 15, g = lid >> 4;

    for (int i = tid; i < 225 * HEADS; i += 256) rpbs[i] = rpb[i];
    __syncthreads();

    const fx4 z = (fx4){0.f, 0.f, 0.f, 0.f};

    for (int hq = wid; hq < HEADS; hq += 4) {
        const unsigned short* qp = q + (size_t)(wl * 64) * CCH + hq * HD + g * 8;
        const unsigned short* kp = k + (size_t)(wl * 64) * CCH + hq * HD + g * 8;
        bh8 aq[4], bk[4];
#pragma unroll
        for (int mf = 0; mf < 4; ++mf)
            aq[mf] = *(const bh8*)(qp + (size_t)(mf * 16 + li) * CCH);
#pragma unroll
        for (int nf = 0; nf < 4; ++nf)
            bk[nf] = *(const bh8*)(kp + (size_t)(nf * 16 + li) * CCH);

        fx4 s[4][4];
#pragma unroll
        for (int mf = 0; mf < 4; ++mf)
#pragma unroll
            for (int nf = 0; nf < 4; ++nf)
                s[mf][nf] = __builtin_amdgcn_mfma_f32_16x16x32_bf16(aq[mf], bk[nf], z, 0, 0, 0);

        // relative position bias (analytic index)
#pragma unroll
        for (int mf = 0; mf < 4; ++mf)
#pragma unroll
            for (int nf = 0; nf < 4; ++nf)
#pragma unroll
                for (int r = 0; r < 4; ++r) {
                    int tq = mf * 16 + g * 4 + r, tk = nf * 16 + li;
                    int dy = (tq >> 3) - (tk >> 3) + 7;
                    int dx = (tq & 7) - (tk & 7) + 7;
                    s[mf][nf][r] += rpbs[(dy * 15 + dx) * HEADS + hq];
                }

        // softmax across tk (lane group of 16 shares a row set)
        float inv_[4][4];
#pragma unroll
        for (int mf = 0; mf < 4; ++mf)
#pragma unroll
            for (int r = 0; r < 4; ++r) {
                float m = s[mf][0][r];
#pragma unroll
                for (int nf = 1; nf < 4; ++nf) m = fmaxf(m, s[mf][nf][r]);
                m = fmaxf(m, __shfl_xor(m, 1));
                m = fmaxf(m, __shfl_xor(m, 2));
                m = fmaxf(m, __shfl_xor(m, 4));
                m = fmaxf(m, __shfl_xor(m, 8));
                float sum = 0.f;
#pragma unroll
                for (int nf = 0; nf < 4; ++nf) {
                    float e = __expf(s[mf][nf][r] - m);
                    s[mf][nf][r] = e;
                    sum += e;
                }
                sum += __shfl_xor(sum, 1);
                sum += __shfl_xor(sum, 2);
                sum += __shfl_xor(sum, 4);
                sum += __shfl_xor(sum, 8);
                inv_[mf][r] = 1.f / sum;
            }

        // P -> per-wave LDS, bf16, row-major [tq][tk]
#pragma unroll
        for (int mf = 0; mf < 4; ++mf)
#pragma unroll
            for (int nf = 0; nf < 4; ++nf)
#pragma unroll
                for (int r = 0; r < 4; ++r)
                    Pl[wid][mf * 16 + g * 4 + r][nf * 16 + li] =
                        f2bf(s[mf][nf][r] * inv_[mf][r]);

        // O^T = V^T x P^T : D[d][tq]
        fx4 o2[2][4];
#pragma unroll
        for (int m2 = 0; m2 < 2; ++m2)
#pragma unroll
            for (int nf = 0; nf < 4; ++nf) o2[m2][nf] = z;
#pragma unroll
        for (int ks = 0; ks < 2; ++ks) {
            bh8 av[2], bp[4];
#pragma unroll
            for (int m2 = 0; m2 < 2; ++m2)
                av[m2] = *(const bh8*)(v + (size_t)(n * CCH + hq * HD + m2 * 16 + li) * HWP
                                         + winl * 64 + ks * 32 + g * 8);
#pragma unroll
            for (int nf = 0; nf < 4; ++nf)
                bp[nf] = *(const bh8*)&Pl[wid][nf * 16 + li][ks * 32 + g * 8];
#pragma unroll
            for (int m2 = 0; m2 < 2; ++m2)
#pragma unroll
                for (int nf = 0; nf < 4; ++nf)
                    o2[m2][nf] = __builtin_amdgcn_mfma_f32_16x16x32_bf16(
                        av[m2], bp[nf], o2[m2][nf], 0, 0, 0);
        }
#pragma unroll
        for (int nf = 0; nf < 4; ++nf) {
            int tq = nf * 16 + li;
#pragma unroll
            for (int m2 = 0; m2 < 2; ++m2) {
                int d = hq * HD + m2 * 16 + g * 4;
                us4 ov;
                ov[0] = f2bf(o2[m2][nf][0]);
                ov[1] = f2bf(o2[m2][nf][1]);
                ov[2] = f2bf(o2[m2][nf][2]);
                ov[3] = f2bf(o2[m2][nf][3]);
                *(us4*)(o + (size_t)(wl * 64 + tq) * CCH + d) = ov;
            }
        }
    }
}

// ---------------------------------------------------------------------------
extern "C" void kernel_launch(void* const* d_in, const int* in_sizes, int n_in,
                              void* d_out, int out_size, void* d_ws, size_t ws_size,
                              hipStream_t stream) {
    const float* vid  = (const float*)d_in[0];
    const float* qd_w = (const float*)d_in[1];
    const float* qd_b = (const float*)d_in[2];
    const float* qp_w = (const float*)d_in[3];
    const float* qp_b = (const float*)d_in[4];
    const float* kd_w = (const float*)d_in[5];
    const float* kd_b = (const float*)d_in[6];
    const float* kp_w = (const float*)d_in[7];
    const float* kp_b = (const float*)d_in[8];
    const float* vd_w = (const float*)d_in[9];
    const float* vd_b = (const float*)d_in[10];
    const float* vp_w = (const float*)d_in[11];
    const float* vp_b = (const float*)d_in[12];
    const float* rpb  = (const float*)d_in[13];
    const float* pj_w = (const float*)d_in[14];
    const float* pj_b = (const float*)d_in[15];

    unsigned short* ws16 = (unsigned short*)d_ws;
    unsigned short* dA0 = ws16;                 // dwconv q  [c][p] bf16
    unsigned short* dA1 = ws16 + EELEM;
    unsigned short* dA2 = ws16 + 2 * EELEM;
    unsigned short* tr0 = ws16 + 3 * EELEM;     // [p_wg][c] bf16
    unsigned short* tr1 = ws16 + 4 * EELEM;
    unsigned short* tr2 = ws16 + 5 * EELEM;
    unsigned short* Wb  = ws16 + 6 * EELEM;     // 4 x 147456 bf16
    unsigned short* qb  = dA0;                  // reuse: dA dead after trsp
    unsigned short* kb  = dA1;
    unsigned short* vb  = dA2;
    unsigned short* ob  = tr0;                  // reuse: tr dead after GEMMs

    wcvt<<<288, 256, 0, stream>>>(qp_w, kp_w, vp_w, pj_w, Wb);
    dwconv3<<<NIMG * CCH * HH, 192, 0, stream>>>(
        vid, qd_w, qd_b, kd_w, kd_b, vd_w, vd_b, dA0, dA1, dA2);
    trsp<<<dim3(NIMG * HH, 6), 256, 0, stream>>>(dA0, dA1, dA2, tr0, tr1, tr2);

    dim3 gg(PTOT / 128, 3);
    const float scale = 0.17677669529663687f;   // 32^-0.5 folded into q
    pw_gemm<1><<<gg, 256, 0, stream>>>(tr0, Wb,             qp_b, scale, qb, nullptr);
    pw_gemm<1><<<gg, 256, 0, stream>>>(tr1, Wb + WMAT,      kp_b, 1.0f,  kb, nullptr);
    pw_gemm<2><<<gg, 256, 0, stream>>>(tr2, Wb + 2 * WMAT,  vp_b, 1.0f,  vb, nullptr);

    attn<<<NIMG * WINS, 256, 0, stream>>>(qb, kb, vb, rpb, ob);

    pw_gemm<3><<<gg, 256, 0, stream>>>(ob, Wb + 3 * WMAT, pj_b, 1.0f, nullptr, (float*)d_out);
}

// Round 3
// 429.583 us; speedup vs baseline: 3.3364x; 1.1220x over previous
//
#include <hip/hip_runtime.h>

#define CCH 384
#define HH 192
#define WWD 192
#define NIMG 2
#define HWP (HH * WWD)        // 36864 pixels per image
#define PTOT (NIMG * HWP)     // 73728
#define HEADS 12
#define HD 32
#define NWIN 24
#define WINS 576              // windows per image
#define EELEM ((size_t)NIMG * CCH * HWP)   // elems per tensor (28,311,552)
#define WMAT 147456           // 384*384

typedef __attribute__((ext_vector_type(8))) short bh8;            // 8 bf16 (MFMA frag)
typedef __attribute__((ext_vector_type(8))) unsigned short us8;
typedef __attribute__((ext_vector_type(4))) unsigned short us4;
typedef __attribute__((ext_vector_type(4))) float fx4;

__device__ __forceinline__ unsigned short f2bf(float f) {
    unsigned u = __float_as_uint(f);
    u += 0x7fffu + ((u >> 16) & 1u);      // round-to-nearest-even
    return (unsigned short)(u >> 16);
}

// ---------------------------------------------------------------------------
// weights fp32 -> bf16 (qp_w, kp_w, vp_w, proj_w concatenated)
// ---------------------------------------------------------------------------
__global__ __launch_bounds__(256) void wcvt(
    const float* __restrict__ a, const float* __restrict__ b,
    const float* __restrict__ c, const float* __restrict__ d,
    unsigned short* __restrict__ o)
{
    int idx8 = (blockIdx.x * 256 + threadIdx.x) * 8;   // 288 blocks * 256 * 8 = 589824 exact
    int which = idx8 / WMAT;
    int loc = idx8 - which * WMAT;
    const float* s = (which == 0) ? a : (which == 1) ? b : (which == 2) ? c : d;
    float4 v0 = *(const float4*)(s + loc);
    float4 v1 = *(const float4*)(s + loc + 4);
    us8 ov;
    ov[0] = f2bf(v0.x); ov[1] = f2bf(v0.y); ov[2] = f2bf(v0.z); ov[3] = f2bf(v0.w);
    ov[4] = f2bf(v1.x); ov[5] = f2bf(v1.y); ov[6] = f2bf(v1.z); ov[7] = f2bf(v1.w);
    *(us8*)(o + idx8) = ov;
}

// ---------------------------------------------------------------------------
// FUSED depthwise 3x3 + bias + window-gather transpose.
// Block = one 8x8 window; loop over 6 chunks of 64 channels.
// Output: bf16 [p_wg][384] for q,k,v (p_wg = window-gathered pixel order).
// LDS halo: [64 ch][11 rows][17 cols] f32 (rows 0..9 = h0-1..h0+8,
//            cols 0..15 = w0-4..w0+11; odd stride 187 -> 2-way banks = free).
// ---------------------------------------------------------------------------
__global__ __launch_bounds__(256) void dwgather(
    const float* __restrict__ x,
    const float* __restrict__ qw, const float* __restrict__ qb,
    const float* __restrict__ kw, const float* __restrict__ kb,
    const float* __restrict__ vw, const float* __restrict__ vb,
    unsigned short* __restrict__ oq, unsigned short* __restrict__ ok,
    unsigned short* __restrict__ ov)
{
    __shared__ float halo[64 * 11 * 17];

    int widx = blockIdx.x;                  // n*576 + wy*24 + wx
    int n = widx / WINS, wrem = widx - n * WINS;
    int wy = wrem / NWIN, wx = wrem - wy * NWIN;
    int h0 = wy * 8, w0 = wx * 8;
    int tid = threadIdx.x;
    int c = tid & 63, pxg = tid >> 6;

    const float* xn = x + (size_t)n * CCH * HWP;

    for (int cb = 0; cb < 6; ++cb) {
        int cg = cb * 64 + c;
        // per-channel weights + biases into registers
        float wq[9], wk[9], wv[9];
#pragma unroll
        for (int t = 0; t < 9; ++t) {
            wq[t] = qw[cg * 9 + t];
            wk[t] = kw[cg * 9 + t];
            wv[t] = vw[cg * 9 + t];
        }
        float bqv = qb[cg], bkv = kb[cg], bvv = vb[cg];

        __syncthreads();   // previous chunk's compute done before overwrite
        // halo load: 2560 jobs of one float4 each = (64c x 10r x 4seg)
#pragma unroll
        for (int it = 0; it < 10; ++it) {
            int job = it * 256 + tid;
            int seg = job & 3;
            int r   = (job >> 2) % 10;
            int cc  = job / 40;
            int hr  = h0 - 1 + r;
            bool okr = (hr >= 0) && (hr < HH);
            bool okc = !((wx == 0 && seg == 0) || (wx == NWIN - 1 && seg == 3));
            float4 val;
            if (okr && okc)
                val = *(const float4*)(xn + (size_t)(cb * 64 + cc) * HWP
                                          + (size_t)hr * WWD + (w0 - 4) + seg * 4);
            else
                val = make_float4(0.f, 0.f, 0.f, 0.f);
            int bidx = (cc * 11 + r) * 17 + seg * 4;
            halo[bidx + 0] = val.x;
            halo[bidx + 1] = val.y;
            halo[bidx + 2] = val.z;
            halo[bidx + 3] = val.w;
        }
        __syncthreads();

        // compute: this lane owns channel c, pixels pxg*16 .. pxg*16+15
#pragma unroll
        for (int i = 0; i < 16; ++i) {
            int px = pxg * 16 + i;
            int pr = px >> 3, pc = px & 7;
            float sq = 0.f, sk = 0.f, sv = 0.f;
#pragma unroll
            for (int dr = 0; dr < 3; ++dr)
#pragma unroll
                for (int dc = 0; dc < 3; ++dc) {
                    float xv = halo[(c * 11 + pr + dr) * 17 + pc + dc + 3];
                    int t = dr * 3 + dc;
                    sq = fmaf(xv, wq[t], sq);
                    sk = fmaf(xv, wk[t], sk);
                    sv = fmaf(xv, wv[t], sv);
                }
            size_t ob = ((size_t)widx * 64 + px) * CCH + cg;
            oq[ob] = f2bf(sq + bqv);
            ok[ob] = f2bf(sk + bkv);
            ov[ob] = f2bf(sv + bvv);
        }
    }
}

// ---------------------------------------------------------------------------
// bf16 MFMA GEMM over channels. Y: bf16 [p_wg][384] (k contiguous).
// W: bf16 [c_out][384]. 128x128 tile, BK=32, 4 waves, 4x4 16x16 frags/wave.
// ORIENT 1: D[c][p] -> out bf16 [p][c], (acc+bias)*scale      (q, k)
// ORIENT 2: D[p][c] -> out bf16 [n][c][p_local], acc+bias     (v, transposed for attn)
// ORIENT 3: D[p][c] -> out fp32 standard [n][c][h][w], un-gather windows (proj)
// ---------------------------------------------------------------------------
template<int ORIENT>
__global__ __launch_bounds__(256) void pw_gemm(
    const unsigned short* __restrict__ Y, const unsigned short* __restrict__ Wb,
    const float* __restrict__ bias, float scale,
    unsigned short* __restrict__ outb, float* __restrict__ outf)
{
    __shared__ unsigned short Wt[128][40];   // [c_out rows][k], padded
    __shared__ unsigned short Yt[128][40];   // [p rows][k], padded

    int tid = threadIdx.x;
    int pp0 = blockIdx.x * 128;
    int cm0 = blockIdx.y * 128;
    int lid = tid & 63, wid = tid >> 6;
    int wr = wid >> 1, wc = wid & 1;
    int li = lid & 15, g = lid >> 4;
    int srow = tid >> 2;                 // 0..63
    int skoff = (tid & 3) * 8;           // 0,8,16,24

    fx4 acc[4][4];
#pragma unroll
    for (int i = 0; i < 4; ++i)
#pragma unroll
        for (int j = 0; j < 4; ++j) acc[i][j] = (fx4){0.f, 0.f, 0.f, 0.f};

    const unsigned short* WpG = Wb + (size_t)(cm0 + srow) * CCH + skoff;
    const unsigned short* YpG = Y  + (size_t)(pp0 + srow) * CCH + skoff;
    bh8 w0 = *(const bh8*)(WpG);
    bh8 w1 = *(const bh8*)(WpG + (size_t)64 * CCH);
    bh8 y0 = *(const bh8*)(YpG);
    bh8 y1 = *(const bh8*)(YpG + (size_t)64 * CCH);

    typedef unsigned short (*tile_t)[40];
    tile_t Asrc = (ORIENT == 1) ? Wt : Yt;
    tile_t Bsrc = (ORIENT == 1) ? Yt : Wt;

    for (int kt = 0; kt < 12; ++kt) {
        __syncthreads();
        *(bh8*)&Wt[srow][skoff]      = w0;
        *(bh8*)&Wt[64 + srow][skoff] = w1;
        *(bh8*)&Yt[srow][skoff]      = y0;
        *(bh8*)&Yt[64 + srow][skoff] = y1;
        __syncthreads();
        if (kt < 11) {
            int ko = (kt + 1) * 32;
            w0 = *(const bh8*)(WpG + ko);
            w1 = *(const bh8*)(WpG + ko + (size_t)64 * CCH);
            y0 = *(const bh8*)(YpG + ko);
            y1 = *(const bh8*)(YpG + ko + (size_t)64 * CCH);
        }
        bh8 a[4], b[4];
#pragma unroll
        for (int mf = 0; mf < 4; ++mf)
            a[mf] = *(const bh8*)&Asrc[wr * 64 + mf * 16 + li][g * 8];
#pragma unroll
        for (int nf = 0; nf < 4; ++nf)
            b[nf] = *(const bh8*)&Bsrc[wc * 64 + nf * 16 + li][g * 8];
#pragma unroll
        for (int mf = 0; mf < 4; ++mf)
#pragma unroll
            for (int nf = 0; nf < 4; ++nf)
                acc[mf][nf] = __builtin_amdgcn_mfma_f32_16x16x32_bf16(
                    a[mf], b[nf], acc[mf][nf], 0, 0, 0);
    }

    if (ORIENT == 1) {
#pragma unroll
        for (int mf = 0; mf < 4; ++mf) {
            int c = cm0 + wr * 64 + mf * 16 + g * 4;
            float4 bv = *(const float4*)&bias[c];
#pragma unroll
            for (int nf = 0; nf < 4; ++nf) {
                int p = pp0 + wc * 64 + nf * 16 + li;
                us4 o;
                o[0] = f2bf((acc[mf][nf][0] + bv.x) * scale);
                o[1] = f2bf((acc[mf][nf][1] + bv.y) * scale);
                o[2] = f2bf((acc[mf][nf][2] + bv.z) * scale);
                o[3] = f2bf((acc[mf][nf][3] + bv.w) * scale);
                *(us4*)(outb + (size_t)p * CCH + c) = o;
            }
        }
    } else if (ORIENT == 2) {
#pragma unroll
        for (int nf = 0; nf < 4; ++nf) {
            int c = cm0 + wc * 64 + nf * 16 + li;
            float bv = bias[c];
#pragma unroll
            for (int mf = 0; mf < 4; ++mf) {
                int p = pp0 + wr * 64 + mf * 16 + g * 4;
                int n = p / HWP;
                int pl = p - n * HWP;
                us4 o;
                o[0] = f2bf(acc[mf][nf][0] + bv);
                o[1] = f2bf(acc[mf][nf][1] + bv);
                o[2] = f2bf(acc[mf][nf][2] + bv);
                o[3] = f2bf(acc[mf][nf][3] + bv);
                *(us4*)(outb + (size_t)(n * CCH + c) * HWP + pl) = o;
            }
        }
    } else {   // ORIENT 3: fp32 std layout, inverse window gather
#pragma unroll
        for (int nf = 0; nf < 4; ++nf) {
            int c = cm0 + wc * 64 + nf * 16 + li;
            float bv = bias[c];
#pragma unroll
            for (int mf = 0; mf < 4; ++mf) {
                int p = pp0 + wr * 64 + mf * 16 + g * 4;
                int n = p / HWP;
                int rem = p - n * HWP;
                int win = rem >> 6, t = rem & 63;
                int h = (win / NWIN) * 8 + (t >> 3);
                int w = (win % NWIN) * 8 + (t & 7);
                float4 o;
                o.x = acc[mf][nf][0] + bv;
                o.y = acc[mf][nf][1] + bv;
                o.z = acc[mf][nf][2] + bv;
                o.w = acc[mf][nf][3] + bv;
                *(float4*)(outf + (size_t)(n * CCH + c) * HWP + h * WWD + w) = o;
            }
        }
    }
}

// ---------------------------------------------------------------------------
// MFMA window attention. block = one window (64 tokens); 4 waves x 3 heads.
// q,k: bf16 [p_wg][384]; v: bf16 [n][c][p_local] (= V^T); out: bf16 [p_wg][384].
// ---------------------------------------------------------------------------
__global__ __launch_bounds__(256) void attn(
    const unsigned short* __restrict__ q, const unsigned short* __restrict__ k,
    const unsigned short* __restrict__ v, const float* __restrict__ rpb,
    unsigned short* __restrict__ o)
{
    __shared__ float rpbs[225 * HEADS];
    __shared__ unsigned short Pl[4][64][72];

    int tid = threadIdx.x, lid = tid & 63, wid = tid >> 6;
    int wl = blockIdx.x;
    int n = wl / WINS, winl = wl - n * WINS;
    int li = lid & 15, g = lid >> 4;

    for (int i = tid; i < 225 * HEADS; i += 256) rpbs[i] = rpb[i];
    __syncthreads();

    const fx4 z = (fx4){0.f, 0.f, 0.f, 0.f};

    for (int hq = wid; hq < HEADS; hq += 4) {
        const unsigned short* qp = q + (size_t)(wl * 64) * CCH + hq * HD + g * 8;
        const unsigned short* kp = k + (size_t)(wl * 64) * CCH + hq * HD + g * 8;
        bh8 aq[4], bk[4];
#pragma unroll
        for (int mf = 0; mf < 4; ++mf)
            aq[mf] = *(const bh8*)(qp + (size_t)(mf * 16 + li) * CCH);
#pragma unroll
        for (int nf = 0; nf < 4; ++nf)
            bk[nf] = *(const bh8*)(kp + (size_t)(nf * 16 + li) * CCH);

        fx4 s[4][4];
#pragma unroll
        for (int mf = 0; mf < 4; ++mf)
#pragma unroll
            for (int nf = 0; nf < 4; ++nf)
                s[mf][nf] = __builtin_amdgcn_mfma_f32_16x16x32_bf16(aq[mf], bk[nf], z, 0, 0, 0);

        // relative position bias (analytic index)
#pragma unroll
        for (int mf = 0; mf < 4; ++mf)
#pragma unroll
            for (int nf = 0; nf < 4; ++nf)
#pragma unroll
                for (int r = 0; r < 4; ++r) {
                    int tq = mf * 16 + g * 4 + r, tk = nf * 16 + li;
                    int dy = (tq >> 3) - (tk >> 3) + 7;
                    int dx = (tq & 7) - (tk & 7) + 7;
                    s[mf][nf][r] += rpbs[(dy * 15 + dx) * HEADS + hq];
                }

        // softmax across tk (lane group of 16 shares a row set)
        float inv_[4][4];
#pragma unroll
        for (int mf = 0; mf < 4; ++mf)
#pragma unroll
            for (int r = 0; r < 4; ++r) {
                float m = s[mf][0][r];
#pragma unroll
                for (int nf = 1; nf < 4; ++nf) m = fmaxf(m, s[mf][nf][r]);
                m = fmaxf(m, __shfl_xor(m, 1));
                m = fmaxf(m, __shfl_xor(m, 2));
                m = fmaxf(m, __shfl_xor(m, 4));
                m = fmaxf(m, __shfl_xor(m, 8));
                float sum = 0.f;
#pragma unroll
                for (int nf = 0; nf < 4; ++nf) {
                    float e = __expf(s[mf][nf][r] - m);
                    s[mf][nf][r] = e;
                    sum += e;
                }
                sum += __shfl_xor(sum, 1);
                sum += __shfl_xor(sum, 2);
                sum += __shfl_xor(sum, 4);
                sum += __shfl_xor(sum, 8);
                inv_[mf][r] = 1.f / sum;
            }

        // P -> per-wave LDS, bf16, row-major [tq][tk]
#pragma unroll
        for (int mf = 0; mf < 4; ++mf)
#pragma unroll
            for (int nf = 0; nf < 4; ++nf)
#pragma unroll
                for (int r = 0; r < 4; ++r)
                    Pl[wid][mf * 16 + g * 4 + r][nf * 16 + li] =
                        f2bf(s[mf][nf][r] * inv_[mf][r]);

        // O^T = V^T x P^T : D[d][tq]
        fx4 o2[2][4];
#pragma unroll
        for (int m2 = 0; m2 < 2; ++m2)
#pragma unroll
            for (int nf = 0; nf < 4; ++nf) o2[m2][nf] = z;
#pragma unroll
        for (int ks = 0; ks < 2; ++ks) {
            bh8 av[2], bp[4];
#pragma unroll
            for (int m2 = 0; m2 < 2; ++m2)
                av[m2] = *(const bh8*)(v + (size_t)(n * CCH + hq * HD + m2 * 16 + li) * HWP
                                         + winl * 64 + ks * 32 + g * 8);
#pragma unroll
            for (int nf = 0; nf < 4; ++nf)
                bp[nf] = *(const bh8*)&Pl[wid][nf * 16 + li][ks * 32 + g * 8];
#pragma unroll
            for (int m2 = 0; m2 < 2; ++m2)
#pragma unroll
                for (int nf = 0; nf < 4; ++nf)
                    o2[m2][nf] = __builtin_amdgcn_mfma_f32_16x16x32_bf16(
                        av[m2], bp[nf], o2[m2][nf], 0, 0, 0);
        }
#pragma unroll
        for (int nf = 0; nf < 4; ++nf) {
            int tq = nf * 16 + li;
#pragma unroll
            for (int m2 = 0; m2 < 2; ++m2) {
                int d = hq * HD + m2 * 16 + g * 4;
                us4 ov;
                ov[0] = f2bf(o2[m2][nf][0]);
                ov[1] = f2bf(o2[m2][nf][1]);
                ov[2] = f2bf(o2[m2][nf][2]);
                ov[3] = f2bf(o2[m2][nf][3]);
                *(us4*)(o + (size_t)(wl * 64 + tq) * CCH + d) = ov;
            }
        }
    }
}

// ---------------------------------------------------------------------------
extern "C" void kernel_launch(void* const* d_in, const int* in_sizes, int n_in,
                              void* d_out, int out_size, void* d_ws, size_t ws_size,
                              hipStream_t stream) {
    const float* vid  = (const float*)d_in[0];
    const float* qd_w = (const float*)d_in[1];
    const float* qd_b = (const float*)d_in[2];
    const float* qp_w = (const float*)d_in[3];
    const float* qp_b = (const float*)d_in[4];
    const float* kd_w = (const float*)d_in[5];
    const float* kd_b = (const float*)d_in[6];
    const float* kp_w = (const float*)d_in[7];
    const float* kp_b = (const float*)d_in[8];
    const float* vd_w = (const float*)d_in[9];
    const float* vd_b = (const float*)d_in[10];
    const float* vp_w = (const float*)d_in[11];
    const float* vp_b = (const float*)d_in[12];
    const float* rpb  = (const float*)d_in[13];
    const float* pj_w = (const float*)d_in[14];
    const float* pj_b = (const float*)d_in[15];

    unsigned short* ws16 = (unsigned short*)d_ws;
    unsigned short* tr0 = ws16 + 3 * EELEM;     // [p_wg][c] bf16 (q,k,v pre-GEMM)
    unsigned short* tr1 = ws16 + 4 * EELEM;
    unsigned short* tr2 = ws16 + 5 * EELEM;
    unsigned short* Wb  = ws16 + 6 * EELEM;     // 4 x 147456 bf16
    unsigned short* qb  = ws16;                 // post-GEMM q,k,v
    unsigned short* kb  = ws16 + EELEM;
    unsigned short* vb  = ws16 + 2 * EELEM;
    unsigned short* ob  = tr0;                  // attn out reuses tr region

    wcvt<<<288, 256, 0, stream>>>(qp_w, kp_w, vp_w, pj_w, Wb);
    dwgather<<<NIMG * WINS, 256, 0, stream>>>(
        vid, qd_w, qd_b, kd_w, kd_b, vd_w, vd_b, tr0, tr1, tr2);

    dim3 gg(PTOT / 128, 3);
    const float scale = 0.17677669529663687f;   // 32^-0.5 folded into q
    pw_gemm<1><<<gg, 256, 0, stream>>>(tr0, Wb,             qp_b, scale, qb, nullptr);
    pw_gemm<1><<<gg, 256, 0, stream>>>(tr1, Wb + WMAT,      kp_b, 1.0f,  kb, nullptr);
    pw_gemm<2><<<gg, 256, 0, stream>>>(tr2, Wb + 2 * WMAT,  vp_b, 1.0f,  vb, nullptr);

    attn<<<NIMG * WINS, 256, 0, stream>>>(qb, kb, vb, rpb, ob);

    pw_gemm<3><<<gg, 256, 0, stream>>>(ob, Wb + 3 * WMAT, pj_b, 1.0f, nullptr, (float*)d_out);
}